// Round 13
// baseline (448.280 us; speedup 1.0000x reference)
//
#include <hip/hip_runtime.h>
#include <stdint.h>

using bf16x8 = __attribute__((ext_vector_type(8))) __bf16;
using f32x4  = __attribute__((ext_vector_type(4))) float;
using f32x16 = __attribute__((ext_vector_type(16))) float;
using us4    = __attribute__((ext_vector_type(4))) unsigned short;
using f4     = __attribute__((ext_vector_type(4))) float;

__device__ __forceinline__ unsigned short f2bf(float f) {
  unsigned u = __builtin_bit_cast(unsigned, f);
  return (unsigned short)((u + 0x7fffu + ((u >> 16) & 1u)) >> 16);  // RTNE
}

__device__ __forceinline__ unsigned cvt_pk_bf16(float lo, float hi) {
  unsigned r;
  asm("v_cvt_pk_bf16_f32 %0, %1, %2" : "=v"(r) : "v"(lo), "v"(hi));
  return r;
}

__device__ __forceinline__ void gload_lds16(const unsigned short* g, unsigned short* l) {
  __builtin_amdgcn_global_load_lds(
      (const __attribute__((address_space(1))) unsigned int*)g,
      (__attribute__((address_space(3))) unsigned int*)l, 16, 0, 0);
}

// scores in log2 domain: fold (1/sqrt(64)) * log2(e) into Q
#define QSCALE 0.18033688011112043f

// ---------------- fp32 -> bf16 elementwise ----------------
__global__ __launch_bounds__(256) void cvt_bf16_kernel(const float* __restrict__ x,
                                                       unsigned short* __restrict__ y, int n) {
  int i = (blockIdx.x * 256 + threadIdx.x) * 4;
  if (i >= n) return;
  f4 v = *(const f4*)(x + i);
  us4 o;
#pragma unroll
  for (int j = 0; j < 4; ++j) o[j] = f2bf(v[j]);
  *(us4*)(y + i) = o;
}

// ---------------- W [K][N] fp32 -> Wt [N][K] bf16 ----------------
__global__ __launch_bounds__(256) void transpose_cvt_kernel(const float* __restrict__ W,
                                                            unsigned short* __restrict__ Wt,
                                                            int K, int N) {
  __shared__ float tile[32][33];
  int n0 = blockIdx.x * 32, k0 = blockIdx.y * 32;
  int tx = threadIdx.x & 31, ty = threadIdx.x >> 5;
#pragma unroll
  for (int i = 0; i < 4; ++i)
    tile[ty + i * 8][tx] = W[(size_t)(k0 + ty + i * 8) * N + n0 + tx];
  __syncthreads();
#pragma unroll
  for (int i = 0; i < 4; ++i)
    Wt[(size_t)(n0 + ty + i * 8) * K + k0 + tx] = f2bf(tile[tx][ty + i * 8]);
}

// ---------------- 32x32-MFMA dbuf bf16 GEMM (QKV) ----------------
// R11 structure (best measured QKV: 94 us, coalesced staging, chunk-XOR) with
// __launch_bounds__(256,3): 48 KB dbuf x 3 blocks/CU = 144 KB -> 3 independent
// blocks/CU so cross-block overlap covers the per-tile vmcnt(0) drain (m114).
template <int MODE, int GN>
__global__ __launch_bounds__(256, 3) void gemmW_kernel(
    const unsigned short* __restrict__ A, const unsigned short* __restrict__ Bt,
    const float* __restrict__ bias, float* __restrict__ outF,
    unsigned short* __restrict__ outQ, unsigned short* __restrict__ outK,
    unsigned short* __restrict__ outV, int N, int K) {
  __shared__ unsigned short As[2][256 * 32];  // 16 KB / buf
  __shared__ unsigned short Bs[2][128 * 32];  // 8 KB / buf   (48 KB total)
  const int tid = threadIdx.x;
  const int lane = tid & 63, wave = tid >> 6;
  const int l31 = lane & 31, lhi = lane >> 5;
  const int wr = wave >> 1, wc = wave & 1;  // 2M x 2N

  const int nwg = gridDim.x, cpx = nwg >> 3;  // bijective XCD swizzle (grid%8==0)
  const int id = (blockIdx.x & 7) * cpx + (blockIdx.x >> 3);
  const int bm = id / GN, bn = id % GN;

  const unsigned short* Ab = A + (size_t)bm * 256 * K;
  const unsigned short* Bb = Bt + (size_t)bn * 128 * K;
  const int NT = K >> 5;

  auto stage = [&](int buf, int T) {
#pragma unroll
    for (int i = 0; i < 6; ++i) {
      int ci = i * 256 + tid;
      if (ci < 1024) {
        int r = ci >> 2, c = ci & 3, cs = c ^ ((r >> 1) & 3);
        gload_lds16(Ab + (size_t)r * K + T * 32 + cs * 8, &As[buf][ci * 8]);
      } else {
        int cj = ci - 1024;
        int r = cj >> 2, c = cj & 3, cs = c ^ ((r >> 1) & 3);
        gload_lds16(Bb + (size_t)r * K + T * 32 + cs * 8, &Bs[buf][cj * 8]);
      }
    }
  };
  const int sw = (l31 >> 1) & 3;
  const int ck0 = (0 * 2 + lhi) ^ sw;
  const int ck1 = (1 * 2 + lhi) ^ sw;

  f32x16 acc[4][2] = {};

  stage(0, 0);
  asm volatile("s_waitcnt vmcnt(0)" ::: "memory");
  __builtin_amdgcn_s_barrier();

#pragma unroll 1
  for (int T = 0; T < NT; ++T) {
    const int cur = T & 1;
    const unsigned short* Ac = &As[cur][0];
    const unsigned short* Bc = &Bs[cur][0];
    bf16x8 af[4][2], bf[2][2];
#pragma unroll
    for (int mm = 0; mm < 4; ++mm) {
      const unsigned short* ar = Ac + (wr * 128 + mm * 32 + l31) * 32;
      af[mm][0] = *(const bf16x8*)(ar + ck0 * 8);
      af[mm][1] = *(const bf16x8*)(ar + ck1 * 8);
    }
#pragma unroll
    for (int nn = 0; nn < 2; ++nn) {
      const unsigned short* br = Bc + (wc * 64 + nn * 32 + l31) * 32;
      bf[nn][0] = *(const bf16x8*)(br + ck0 * 8);
      bf[nn][1] = *(const bf16x8*)(br + ck1 * 8);
    }
    if (T + 1 < NT) stage(cur ^ 1, T + 1);
#pragma unroll
    for (int mm = 0; mm < 4; ++mm)
#pragma unroll
      for (int nn = 0; nn < 2; ++nn) {
        acc[mm][nn] = __builtin_amdgcn_mfma_f32_32x32x16_bf16(af[mm][0], bf[nn][0],
                                                              acc[mm][nn], 0, 0, 0);
        acc[mm][nn] = __builtin_amdgcn_mfma_f32_32x32x16_bf16(af[mm][1], bf[nn][1],
                                                              acc[mm][nn], 0, 0, 0);
      }
    if (T + 1 < NT) asm volatile("s_waitcnt vmcnt(0)" ::: "memory");
    __builtin_amdgcn_s_barrier();
  }

  // epilogue: C/D map col=lane&31, row=(reg&3)+8*(reg>>2)+4*(lane>>5)
#pragma unroll
  for (int mm = 0; mm < 4; ++mm) {
#pragma unroll
    for (int nn = 0; nn < 2; ++nn) {
      const int gc0 = bn * 128 + wc * 64 + nn * 32;  // wave-uniform
      const float bi = bias[gc0 + l31];
      if (MODE == 0) {
#pragma unroll
        for (int reg = 0; reg < 16; ++reg) {
          int gr = bm * 256 + wr * 128 + mm * 32 + (reg & 3) + 8 * (reg >> 2) + 4 * lhi;
          outF[(size_t)gr * N + gc0 + l31] = acc[mm][nn][reg] + bi;
        }
      } else {
        const int head = gc0 / 192;          // uniform per fragment
        const int j0 = gc0 - head * 192;     // 0,32 =Q; 64,96 =K; 128,160 =V
        if (j0 < 128) {
          unsigned short* dst = (j0 < 64) ? outQ : outK;
          const int joff = (j0 < 64) ? j0 : (j0 - 64);
          const float sc = (j0 < 64) ? QSCALE : 1.0f;
#pragma unroll
          for (int reg = 0; reg < 16; ++reg) {
            int gr = bm * 256 + wr * 128 + mm * 32 + (reg & 3) + 8 * (reg >> 2) + 4 * lhi;
            int b = gr >> 11, l = gr & 2047;
            dst[((size_t)(b * 16 + head) * 2048 + l) * 64 + joff + l31] =
                f2bf((acc[mm][nn][reg] + bi) * sc);
          }
        } else {
          const int d = j0 - 128 + l31;
#pragma unroll
          for (int reg = 0; reg < 16; ++reg) {
            int gr = bm * 256 + wr * 128 + mm * 32 + (reg & 3) + 8 * (reg >> 2) + 4 * lhi;
            int b = gr >> 11, l = gr & 2047;
            outV[((size_t)(b * 16 + head) * 64 + d) * 2048 + l] = f2bf(acc[mm][nn][reg] + bi);
          }
        }
      }
    }
  }
}

// ---------------- out-proj: R7's triple-buffered 128x256 gemm3 (measured best) ----------------
template <int MODE, int GN>
__global__ __launch_bounds__(512, 2) void gemm3_kernel(
    const unsigned short* __restrict__ A, const unsigned short* __restrict__ Bt,
    const float* __restrict__ bias, float* __restrict__ outF,
    unsigned short* __restrict__ outQ, unsigned short* __restrict__ outK,
    unsigned short* __restrict__ outV, int N, int K) {
  __shared__ unsigned short As[3][128 * 64];  // 16 KB / buf
  __shared__ unsigned short Bs[3][256 * 64];  // 32 KB / buf  (total 144 KB)
  const int tid = threadIdx.x;
  const int lane = tid & 63, wave = tid >> 6;
  const int l16 = lane & 15, lhi = lane >> 4;
  const int wr = wave >> 2, wc = wave & 3;  // 2M x 4N

  const int nwg = gridDim.x, cpx = nwg >> 3;
  const int id = (blockIdx.x & 7) * cpx + (blockIdx.x >> 3);
  const int bm = id / GN, bn = id % GN;

  const unsigned short* Ab = A + (size_t)bm * 128 * K;
  const unsigned short* Bb = Bt + (size_t)bn * 256 * K;
  const int NT = K >> 6;

  const int s3 = l16 & 7;
  const int c0 = lhi ^ s3;
  const int c1 = c0 ^ 4;

  auto stageA = [&](int buf, int T) {
#pragma unroll
    for (int i = 0; i < 2; ++i) {
      int ci = i * 512 + tid;
      int r = ci >> 3, cs = (ci & 7) ^ (r & 7);
      gload_lds16(Ab + (size_t)r * K + T * 64 + cs * 8, &As[buf][ci * 8]);
    }
  };
  auto stageB = [&](int buf, int T, int half) {
#pragma unroll
    for (int i = 0; i < 2; ++i) {
      int ci = half * 1024 + i * 512 + tid;
      int r = ci >> 3, cs = (ci & 7) ^ (r & 7);
      gload_lds16(Bb + (size_t)r * K + T * 64 + cs * 8, &Bs[buf][ci * 8]);
    }
  };

  f32x4 acc[4][4] = {};

  stageA(0, 0); stageB(0, 0, 0); stageB(0, 0, 1);
  stageA(1, 1); stageB(1, 1, 0); stageB(1, 1, 1);
  asm volatile("s_waitcnt vmcnt(6)" ::: "memory");
  __builtin_amdgcn_s_barrier();

  int bR = 0;
#pragma unroll 1
  for (int T = 0; T < NT; ++T) {
    int bS = bR + 2;
    if (bS >= 3) bS -= 3;
    const unsigned short* Ac = &As[bR][0];
    const unsigned short* Bc = &Bs[bR][0];

    bf16x8 a0[4], a1[4], b0[4], b1[4];
#pragma unroll
    for (int m = 0; m < 4; ++m) {
      a0[m] = *(const bf16x8*)(Ac + (wr * 64 + m * 16 + l16) * 64 + c0 * 8);
      a1[m] = *(const bf16x8*)(Ac + (wr * 64 + m * 16 + l16) * 64 + c1 * 8);
    }
#pragma unroll
    for (int n = 0; n < 4; ++n) {
      b0[n] = *(const bf16x8*)(Bc + (wc * 64 + n * 16 + l16) * 64 + c0 * 8);
      b1[n] = *(const bf16x8*)(Bc + (wc * 64 + n * 16 + l16) * 64 + c1 * 8);
    }
    if (T + 2 < NT) {
      stageA(bS, T + 2);
      stageB(bS, T + 2, 0);
      stageB(bS, T + 2, 1);
    }
    __builtin_amdgcn_s_setprio(1);
#pragma unroll
    for (int m = 0; m < 4; ++m)
#pragma unroll
      for (int n = 0; n < 4; ++n)
        acc[m][n] = __builtin_amdgcn_mfma_f32_16x16x32_bf16(a0[m], b0[n], acc[m][n], 0, 0, 0);
#pragma unroll
    for (int m = 0; m < 4; ++m)
#pragma unroll
      for (int n = 0; n < 4; ++n)
        acc[m][n] = __builtin_amdgcn_mfma_f32_16x16x32_bf16(a1[m], b1[n], acc[m][n], 0, 0, 0);
    __builtin_amdgcn_s_setprio(0);
    if (T + 2 < NT)
      asm volatile("s_waitcnt vmcnt(6)" ::: "memory");
    else if (T + 1 < NT)
      asm volatile("s_waitcnt vmcnt(0)" ::: "memory");
    __builtin_amdgcn_s_barrier();
    bR = bR + 1;
    if (bR == 3) bR = 0;
  }

#pragma unroll
  for (int m = 0; m < 4; ++m) {
#pragma unroll
    for (int n = 0; n < 4; ++n) {
#pragma unroll
      for (int r = 0; r < 4; ++r) {
        int gr = bm * 128 + wr * 64 + m * 16 + lhi * 4 + r;
        int gc = bn * 256 + wc * 64 + n * 16 + l16;
        float v = acc[m][n][r] + bias[gc];
        if (MODE == 0) {
          outF[(size_t)gr * N + gc] = v;
        } else {
          int b = gr >> 11, l = gr & 2047;
          int head = gc / 192, j = gc - head * 192;
          size_t base = ((size_t)(b * 16 + head) * 2048 + l) * 64;
          if (j < 64)
            outQ[base + j] = f2bf(v * QSCALE);
          else if (j < 128)
            outK[base + (j - 64)] = f2bf(v);
          else
            outV[((size_t)(b * 16 + head) * 64 + (j - 128)) * 2048 + l] = f2bf(v);
        }
      }
    }
  }
}

// ---------------- causal flash attention v3 (unchanged) ----------------
__global__ __launch_bounds__(256) void attn_kernel(const unsigned short* __restrict__ Q,
                                                   const unsigned short* __restrict__ K,
                                                   const unsigned short* __restrict__ Vt,
                                                   unsigned short* __restrict__ Ao) {
  __shared__ unsigned short Ks[2][4096];
  __shared__ unsigned short Vs[2][4096];
  __shared__ unsigned short Plds[4][1024];

  const int qtA = blockIdx.x, bh = blockIdx.y;
  const int tid = threadIdx.x;
  const int lane = tid & 63, wave = tid >> 6;
  const int l16 = lane & 15, lhi = lane >> 4;

  const unsigned short* Qp = Q + (size_t)bh * 2048 * 64;
  const unsigned short* Kp = K + (size_t)bh * 2048 * 64;
  const unsigned short* Vp = Vt + (size_t)bh * 64 * 2048;
  const int b = bh >> 4, h = bh & 15;

  const int swz = (l16 & 7) << 3;
  const int kc0 = (lhi * 16) ^ ((l16 & 7) << 4);

  auto stage = [&](int buf, int k0) {
#pragma unroll
    for (int i = 0; i < 2; ++i) {
      int c = tid + 256 * i;
      int row = c >> 3;
      int col16 = (c & 7) ^ (row & 7);
      gload_lds16(Kp + (size_t)(k0 + row) * 64 + col16 * 8, &Ks[buf][c * 8]);
      gload_lds16(Vp + (size_t)row * 2048 + k0 + col16 * 8, &Vs[buf][c * 8]);
    }
  };

#pragma unroll 1
  for (int phase = 0; phase < 2; ++phase) {
    const int qt = phase ? (31 - qtA) : qtA;
    const int qbase = qt * 64 + wave * 16;
    const int qrow = qbase + l16;
    const int ntile = qt + 1;

    stage(0, 0);
    bf16x8 qf0 = *(const bf16x8*)&Qp[(size_t)(qbase + l16) * 64 + lhi * 8];
    bf16x8 qf1 = *(const bf16x8*)&Qp[(size_t)(qbase + l16) * 64 + 32 + lhi * 8];

    f32x4 o[4] = {};
    float mi = -1e30f, li = 0.f;

    asm volatile("s_waitcnt vmcnt(0)" ::: "memory");
    __syncthreads();

    int cur = 0;
#pragma unroll 1
    for (int kt = 0; kt < ntile; ++kt) {
      const int k0 = kt * 64;
      if (kt + 1 < ntile) stage(cur ^ 1, k0 + 64);

      const char* kb = (const char*)Ks[cur];
      f32x4 st[4];
      __builtin_amdgcn_s_setprio(1);
#pragma unroll
      for (int j = 0; j < 4; ++j) {
        const char* kr = kb + (16 * j + l16) * 128;
        bf16x8 kf0 = *(const bf16x8*)(kr + kc0);
        bf16x8 kf1 = *(const bf16x8*)(kr + (kc0 ^ 64));
        f32x4 z = {};
        z = __builtin_amdgcn_mfma_f32_16x16x32_bf16(kf0, qf0, z, 0, 0, 0);
        st[j] = __builtin_amdgcn_mfma_f32_16x16x32_bf16(kf1, qf1, z, 0, 0, 0);
      }
      __builtin_amdgcn_s_setprio(0);

      float p[16];
      float mv = -1e30f;
      if (k0 + 63 <= qbase) {
#pragma unroll
        for (int j = 0; j < 4; ++j)
#pragma unroll
          for (int r = 0; r < 4; ++r) {
            float v = st[j][r];
            p[j * 4 + r] = v;
            mv = fmaxf(mv, v);
          }
      } else {
#pragma unroll
        for (int j = 0; j < 4; ++j)
#pragma unroll
          for (int r = 0; r < 4; ++r) {
            int key = k0 + 16 * j + 4 * lhi + r;
            float v = (key <= qrow) ? st[j][r] : -1e30f;
            p[j * 4 + r] = v;
            mv = fmaxf(mv, v);
          }
      }
      mv = fmaxf(mv, __shfl_xor(mv, 16));
      mv = fmaxf(mv, __shfl_xor(mv, 32));
      if (!__all(mv <= mi + 8.0f)) {
        float mnew = fmaxf(mi, mv);
        float alpha = __builtin_amdgcn_exp2f(mi - mnew);
#pragma unroll
        for (int c = 0; c < 4; ++c)
#pragma unroll
          for (int r = 0; r < 4; ++r) o[c][r] *= alpha;
        li *= alpha;
        mi = mnew;
      }
      float sum = 0.f;
#pragma unroll
      for (int i = 0; i < 16; ++i) {
        p[i] = __builtin_amdgcn_exp2f(p[i] - mi);
        sum += p[i];
      }
      sum += __shfl_xor(sum, 16);
      sum += __shfl_xor(sum, 32);
      li += sum;

#pragma unroll
      for (int j = 0; j < 4; ++j) {
        uint2 w;
        w.x = cvt_pk_bf16(p[j * 4 + 0], p[j * 4 + 1]);
        w.y = cvt_pk_bf16(p[j * 4 + 2], p[j * 4 + 3]);
        *(uint2*)&Plds[wave][l16 * 64 + ((j * 16 + 4 * lhi) ^ swz)] = w;
      }
      asm volatile("s_waitcnt lgkmcnt(0)" ::: "memory");
      __builtin_amdgcn_sched_barrier(0);

      const char* vb = (const char*)Vs[cur];
      __builtin_amdgcn_s_setprio(1);
#pragma unroll
      for (int c2 = 0; c2 < 2; ++c2) {
        bf16x8 pf = *(const bf16x8*)&Plds[wave][l16 * 64 + ((c2 * 32 + lhi * 8) ^ swz)];
#pragma unroll
        for (int c = 0; c < 4; ++c) {
          bf16x8 vf = *(const bf16x8*)(vb + (c * 16 + l16) * 128 + (kc0 ^ (c2 * 64)));
          o[c] = __builtin_amdgcn_mfma_f32_16x16x32_bf16(vf, pf, o[c], 0, 0, 0);
        }
      }
      __builtin_amdgcn_s_setprio(0);

      asm volatile("s_waitcnt vmcnt(0)" ::: "memory");
      __syncthreads();
      cur ^= 1;
    }

    float invl = 1.0f / li;
    size_t rowb = (size_t)(b * 2048 + qbase + l16) * 1024 + h * 64;
#pragma unroll
    for (int c = 0; c < 4; ++c) {
      uint2 w;
      w.x = cvt_pk_bf16(o[c][0] * invl, o[c][1] * invl);
      w.y = cvt_pk_bf16(o[c][2] * invl, o[c][3] * invl);
      *(uint2*)&Ao[rowb + c * 16 + lhi * 4] = w;
    }
  }
}

extern "C" void kernel_launch(void* const* d_in, const int* in_sizes, int n_in,
                              void* d_out, int out_size, void* d_ws, size_t ws_size,
                              hipStream_t stream) {
  const float* X    = (const float*)d_in[0];
  const float* Wqkv = (const float*)d_in[1];
  const float* bqkv = (const float*)d_in[2];
  const float* Wout = (const float*)d_in[3];
  const float* bout = (const float*)d_in[4];
  float* out = (float*)d_out;

  unsigned short* ws     = (unsigned short*)d_ws;
  unsigned short* Xb     = ws;                   // 8192*1024
  unsigned short* Wqkv_t = Xb + 8388608;         // 3072*1024
  unsigned short* Wout_t = Wqkv_t + 3145728;     // 1024*1024
  unsigned short* Qb     = Wout_t + 1048576;     // [B,H,S,64]
  unsigned short* Kb     = Qb + 8388608;         // [B,H,S,64]
  unsigned short* Vtb    = Kb + 8388608;         // [B,H,64,S]
  unsigned short* Aob    = Vtb + 8388608;        // [B*S,1024]

  cvt_bf16_kernel<<<8192, 256, 0, stream>>>(X, Xb, 8388608);
  transpose_cvt_kernel<<<dim3(3072 / 32, 1024 / 32), 256, 0, stream>>>(Wqkv, Wqkv_t, 1024, 3072);
  transpose_cvt_kernel<<<dim3(1024 / 32, 1024 / 32), 256, 0, stream>>>(Wout, Wout_t, 1024, 1024);
  gemmW_kernel<1, 24><<<768, 256, 0, stream>>>(
      Xb, Wqkv_t, bqkv, nullptr, Qb, Kb, Vtb, 3072, 1024);
  attn_kernel<<<dim3(16, 64), 256, 0, stream>>>(Qb, Kb, Vtb, Aob);
  gemm3_kernel<0, 4><<<256, 512, 0, stream>>>(
      Aob, Wout_t, bout, out, nullptr, nullptr, nullptr, 1024, 1024);
}

// Round 14
// 197.244 us; speedup vs baseline: 2.2727x; 2.2727x over previous
//
#include <hip/hip_runtime.h>
#include <stdint.h>

using bf16x8 = __attribute__((ext_vector_type(8))) __bf16;
using f32x4  = __attribute__((ext_vector_type(4))) float;
using f32x16 = __attribute__((ext_vector_type(16))) float;
using us4    = __attribute__((ext_vector_type(4))) unsigned short;
using f4     = __attribute__((ext_vector_type(4))) float;

__device__ __forceinline__ unsigned short f2bf(float f) {
  unsigned u = __builtin_bit_cast(unsigned, f);
  return (unsigned short)((u + 0x7fffu + ((u >> 16) & 1u)) >> 16);  // RTNE
}

__device__ __forceinline__ unsigned cvt_pk_bf16(float lo, float hi) {
  unsigned r;
  asm("v_cvt_pk_bf16_f32 %0, %1, %2" : "=v"(r) : "v"(lo), "v"(hi));
  return r;
}

__device__ __forceinline__ void gload_lds16(const unsigned short* g, unsigned short* l) {
  __builtin_amdgcn_global_load_lds(
      (const __attribute__((address_space(1))) unsigned int*)g,
      (__attribute__((address_space(3))) unsigned int*)l, 16, 0, 0);
}

// scores in log2 domain: fold (1/sqrt(64)) * log2(e) into Q
#define QSCALE 0.18033688011112043f

// ---------------- fp32 -> bf16 elementwise ----------------
__global__ __launch_bounds__(256) void cvt_bf16_kernel(const float* __restrict__ x,
                                                       unsigned short* __restrict__ y, int n) {
  int i = (blockIdx.x * 256 + threadIdx.x) * 4;
  if (i >= n) return;
  f4 v = *(const f4*)(x + i);
  us4 o;
#pragma unroll
  for (int j = 0; j < 4; ++j) o[j] = f2bf(v[j]);
  *(us4*)(y + i) = o;
}

// ---------------- W [K][N] fp32 -> Wt [N][K] bf16 ----------------
__global__ __launch_bounds__(256) void transpose_cvt_kernel(const float* __restrict__ W,
                                                            unsigned short* __restrict__ Wt,
                                                            int K, int N) {
  __shared__ float tile[32][33];
  int n0 = blockIdx.x * 32, k0 = blockIdx.y * 32;
  int tx = threadIdx.x & 31, ty = threadIdx.x >> 5;
#pragma unroll
  for (int i = 0; i < 4; ++i)
    tile[ty + i * 8][tx] = W[(size_t)(k0 + ty + i * 8) * N + n0 + tx];
  __syncthreads();
#pragma unroll
  for (int i = 0; i < 4; ++i)
    Wt[(size_t)(n0 + ty + i * 8) * K + k0 + tx] = f2bf(tile[tx][ty + i * 8]);
}

// ---------------- 32x32-MFMA dbuf bf16 GEMM (QKV) ----------------
// R11 structure exactly (best measured QKV: 94 us). __launch_bounds__(256,2):
// (256,3) in R13 capped VGPR at 84 < the 128-VGPR accumulator -> scratch
// spills (FETCH 59->388 MB, 354 us). Never tighten bounds past acc footprint.
template <int MODE, int GN>
__global__ __launch_bounds__(256, 2) void gemmW_kernel(
    const unsigned short* __restrict__ A, const unsigned short* __restrict__ Bt,
    const float* __restrict__ bias, float* __restrict__ outF,
    unsigned short* __restrict__ outQ, unsigned short* __restrict__ outK,
    unsigned short* __restrict__ outV, int N, int K) {
  __shared__ unsigned short As[2][256 * 32];  // 16 KB / buf
  __shared__ unsigned short Bs[2][128 * 32];  // 8 KB / buf   (48 KB total)
  const int tid = threadIdx.x;
  const int lane = tid & 63, wave = tid >> 6;
  const int l31 = lane & 31, lhi = lane >> 5;
  const int wr = wave >> 1, wc = wave & 1;  // 2M x 2N

  const int nwg = gridDim.x, cpx = nwg >> 3;  // bijective XCD swizzle (grid%8==0)
  const int id = (blockIdx.x & 7) * cpx + (blockIdx.x >> 3);
  const int bm = id / GN, bn = id % GN;

  const unsigned short* Ab = A + (size_t)bm * 256 * K;
  const unsigned short* Bb = Bt + (size_t)bn * 128 * K;
  const int NT = K >> 5;

  auto stage = [&](int buf, int T) {
#pragma unroll
    for (int i = 0; i < 6; ++i) {
      int ci = i * 256 + tid;
      if (ci < 1024) {
        int r = ci >> 2, c = ci & 3, cs = c ^ ((r >> 1) & 3);
        gload_lds16(Ab + (size_t)r * K + T * 32 + cs * 8, &As[buf][ci * 8]);
      } else {
        int cj = ci - 1024;
        int r = cj >> 2, c = cj & 3, cs = c ^ ((r >> 1) & 3);
        gload_lds16(Bb + (size_t)r * K + T * 32 + cs * 8, &Bs[buf][cj * 8]);
      }
    }
  };
  const int sw = (l31 >> 1) & 3;
  const int ck0 = (0 * 2 + lhi) ^ sw;
  const int ck1 = (1 * 2 + lhi) ^ sw;

  f32x16 acc[4][2] = {};

  stage(0, 0);
  asm volatile("s_waitcnt vmcnt(0)" ::: "memory");
  __builtin_amdgcn_s_barrier();

#pragma unroll 1
  for (int T = 0; T < NT; ++T) {
    const int cur = T & 1;
    const unsigned short* Ac = &As[cur][0];
    const unsigned short* Bc = &Bs[cur][0];
    bf16x8 af[4][2], bf[2][2];
#pragma unroll
    for (int mm = 0; mm < 4; ++mm) {
      const unsigned short* ar = Ac + (wr * 128 + mm * 32 + l31) * 32;
      af[mm][0] = *(const bf16x8*)(ar + ck0 * 8);
      af[mm][1] = *(const bf16x8*)(ar + ck1 * 8);
    }
#pragma unroll
    for (int nn = 0; nn < 2; ++nn) {
      const unsigned short* br = Bc + (wc * 64 + nn * 32 + l31) * 32;
      bf[nn][0] = *(const bf16x8*)(br + ck0 * 8);
      bf[nn][1] = *(const bf16x8*)(br + ck1 * 8);
    }
    if (T + 1 < NT) stage(cur ^ 1, T + 1);
#pragma unroll
    for (int mm = 0; mm < 4; ++mm)
#pragma unroll
      for (int nn = 0; nn < 2; ++nn) {
        acc[mm][nn] = __builtin_amdgcn_mfma_f32_32x32x16_bf16(af[mm][0], bf[nn][0],
                                                              acc[mm][nn], 0, 0, 0);
        acc[mm][nn] = __builtin_amdgcn_mfma_f32_32x32x16_bf16(af[mm][1], bf[nn][1],
                                                              acc[mm][nn], 0, 0, 0);
      }
    if (T + 1 < NT) asm volatile("s_waitcnt vmcnt(0)" ::: "memory");
    __builtin_amdgcn_s_barrier();
  }

  // epilogue: C/D map col=lane&31, row=(reg&3)+8*(reg>>2)+4*(lane>>5)
#pragma unroll
  for (int mm = 0; mm < 4; ++mm) {
#pragma unroll
    for (int nn = 0; nn < 2; ++nn) {
      const int gc0 = bn * 128 + wc * 64 + nn * 32;  // wave-uniform
      const float bi = bias[gc0 + l31];
      if (MODE == 0) {
#pragma unroll
        for (int reg = 0; reg < 16; ++reg) {
          int gr = bm * 256 + wr * 128 + mm * 32 + (reg & 3) + 8 * (reg >> 2) + 4 * lhi;
          outF[(size_t)gr * N + gc0 + l31] = acc[mm][nn][reg] + bi;
        }
      } else {
        const int head = gc0 / 192;          // uniform per fragment
        const int j0 = gc0 - head * 192;     // 0,32 =Q; 64,96 =K; 128,160 =V
        if (j0 < 128) {
          unsigned short* dst = (j0 < 64) ? outQ : outK;
          const int joff = (j0 < 64) ? j0 : (j0 - 64);
          const float sc = (j0 < 64) ? QSCALE : 1.0f;
#pragma unroll
          for (int reg = 0; reg < 16; ++reg) {
            int gr = bm * 256 + wr * 128 + mm * 32 + (reg & 3) + 8 * (reg >> 2) + 4 * lhi;
            int b = gr >> 11, l = gr & 2047;
            dst[((size_t)(b * 16 + head) * 2048 + l) * 64 + joff + l31] =
                f2bf((acc[mm][nn][reg] + bi) * sc);
          }
        } else {
          const int d = j0 - 128 + l31;
#pragma unroll
          for (int reg = 0; reg < 16; ++reg) {
            int gr = bm * 256 + wr * 128 + mm * 32 + (reg & 3) + 8 * (reg >> 2) + 4 * lhi;
            int b = gr >> 11, l = gr & 2047;
            outV[((size_t)(b * 16 + head) * 64 + d) * 2048 + l] = f2bf(acc[mm][nn][reg] + bi);
          }
        }
      }
    }
  }
}

// ---------------- out-proj: R7's triple-buffered 128x256 gemm3 (measured best) ----------------
template <int MODE, int GN>
__global__ __launch_bounds__(512, 2) void gemm3_kernel(
    const unsigned short* __restrict__ A, const unsigned short* __restrict__ Bt,
    const float* __restrict__ bias, float* __restrict__ outF,
    unsigned short* __restrict__ outQ, unsigned short* __restrict__ outK,
    unsigned short* __restrict__ outV, int N, int K) {
  __shared__ unsigned short As[3][128 * 64];  // 16 KB / buf
  __shared__ unsigned short Bs[3][256 * 64];  // 32 KB / buf  (total 144 KB)
  const int tid = threadIdx.x;
  const int lane = tid & 63, wave = tid >> 6;
  const int l16 = lane & 15, lhi = lane >> 4;
  const int wr = wave >> 2, wc = wave & 3;  // 2M x 4N

  const int nwg = gridDim.x, cpx = nwg >> 3;
  const int id = (blockIdx.x & 7) * cpx + (blockIdx.x >> 3);
  const int bm = id / GN, bn = id % GN;

  const unsigned short* Ab = A + (size_t)bm * 128 * K;
  const unsigned short* Bb = Bt + (size_t)bn * 256 * K;
  const int NT = K >> 6;

  const int s3 = l16 & 7;
  const int c0 = lhi ^ s3;
  const int c1 = c0 ^ 4;

  auto stageA = [&](int buf, int T) {
#pragma unroll
    for (int i = 0; i < 2; ++i) {
      int ci = i * 512 + tid;
      int r = ci >> 3, cs = (ci & 7) ^ (r & 7);
      gload_lds16(Ab + (size_t)r * K + T * 64 + cs * 8, &As[buf][ci * 8]);
    }
  };
  auto stageB = [&](int buf, int T, int half) {
#pragma unroll
    for (int i = 0; i < 2; ++i) {
      int ci = half * 1024 + i * 512 + tid;
      int r = ci >> 3, cs = (ci & 7) ^ (r & 7);
      gload_lds16(Bb + (size_t)r * K + T * 64 + cs * 8, &Bs[buf][ci * 8]);
    }
  };

  f32x4 acc[4][4] = {};

  stageA(0, 0); stageB(0, 0, 0); stageB(0, 0, 1);
  stageA(1, 1); stageB(1, 1, 0); stageB(1, 1, 1);
  asm volatile("s_waitcnt vmcnt(6)" ::: "memory");
  __builtin_amdgcn_s_barrier();

  int bR = 0;
#pragma unroll 1
  for (int T = 0; T < NT; ++T) {
    int bS = bR + 2;
    if (bS >= 3) bS -= 3;
    const unsigned short* Ac = &As[bR][0];
    const unsigned short* Bc = &Bs[bR][0];

    bf16x8 a0[4], a1[4], b0[4], b1[4];
#pragma unroll
    for (int m = 0; m < 4; ++m) {
      a0[m] = *(const bf16x8*)(Ac + (wr * 64 + m * 16 + l16) * 64 + c0 * 8);
      a1[m] = *(const bf16x8*)(Ac + (wr * 64 + m * 16 + l16) * 64 + c1 * 8);
    }
#pragma unroll
    for (int n = 0; n < 4; ++n) {
      b0[n] = *(const bf16x8*)(Bc + (wc * 64 + n * 16 + l16) * 64 + c0 * 8);
      b1[n] = *(const bf16x8*)(Bc + (wc * 64 + n * 16 + l16) * 64 + c1 * 8);
    }
    if (T + 2 < NT) {
      stageA(bS, T + 2);
      stageB(bS, T + 2, 0);
      stageB(bS, T + 2, 1);
    }
    __builtin_amdgcn_s_setprio(1);
#pragma unroll
    for (int m = 0; m < 4; ++m)
#pragma unroll
      for (int n = 0; n < 4; ++n)
        acc[m][n] = __builtin_amdgcn_mfma_f32_16x16x32_bf16(a0[m], b0[n], acc[m][n], 0, 0, 0);
#pragma unroll
    for (int m = 0; m < 4; ++m)
#pragma unroll
      for (int n = 0; n < 4; ++n)
        acc[m][n] = __builtin_amdgcn_mfma_f32_16x16x32_bf16(a1[m], b1[n], acc[m][n], 0, 0, 0);
    __builtin_amdgcn_s_setprio(0);
    if (T + 2 < NT)
      asm volatile("s_waitcnt vmcnt(6)" ::: "memory");
    else if (T + 1 < NT)
      asm volatile("s_waitcnt vmcnt(0)" ::: "memory");
    __builtin_amdgcn_s_barrier();
    bR = bR + 1;
    if (bR == 3) bR = 0;
  }

#pragma unroll
  for (int m = 0; m < 4; ++m) {
#pragma unroll
    for (int n = 0; n < 4; ++n) {
#pragma unroll
      for (int r = 0; r < 4; ++r) {
        int gr = bm * 128 + wr * 64 + m * 16 + lhi * 4 + r;
        int gc = bn * 256 + wc * 64 + n * 16 + l16;
        float v = acc[m][n][r] + bias[gc];
        if (MODE == 0) {
          outF[(size_t)gr * N + gc] = v;
        } else {
          int b = gr >> 11, l = gr & 2047;
          int head = gc / 192, j = gc - head * 192;
          size_t base = ((size_t)(b * 16 + head) * 2048 + l) * 64;
          if (j < 64)
            outQ[base + j] = f2bf(v * QSCALE);
          else if (j < 128)
            outK[base + (j - 64)] = f2bf(v);
          else
            outV[((size_t)(b * 16 + head) * 64 + (j - 128)) * 2048 + l] = f2bf(v);
        }
      }
    }
  }
}

// ---------------- causal flash attention v3 (unchanged) ----------------
__global__ __launch_bounds__(256) void attn_kernel(const unsigned short* __restrict__ Q,
                                                   const unsigned short* __restrict__ K,
                                                   const unsigned short* __restrict__ Vt,
                                                   unsigned short* __restrict__ Ao) {
  __shared__ unsigned short Ks[2][4096];
  __shared__ unsigned short Vs[2][4096];
  __shared__ unsigned short Plds[4][1024];

  const int qtA = blockIdx.x, bh = blockIdx.y;
  const int tid = threadIdx.x;
  const int lane = tid & 63, wave = tid >> 6;
  const int l16 = lane & 15, lhi = lane >> 4;

  const unsigned short* Qp = Q + (size_t)bh * 2048 * 64;
  const unsigned short* Kp = K + (size_t)bh * 2048 * 64;
  const unsigned short* Vp = Vt + (size_t)bh * 64 * 2048;
  const int b = bh >> 4, h = bh & 15;

  const int swz = (l16 & 7) << 3;
  const int kc0 = (lhi * 16) ^ ((l16 & 7) << 4);

  auto stage = [&](int buf, int k0) {
#pragma unroll
    for (int i = 0; i < 2; ++i) {
      int c = tid + 256 * i;
      int row = c >> 3;
      int col16 = (c & 7) ^ (row & 7);
      gload_lds16(Kp + (size_t)(k0 + row) * 64 + col16 * 8, &Ks[buf][c * 8]);
      gload_lds16(Vp + (size_t)row * 2048 + k0 + col16 * 8, &Vs[buf][c * 8]);
    }
  };

#pragma unroll 1
  for (int phase = 0; phase < 2; ++phase) {
    const int qt = phase ? (31 - qtA) : qtA;
    const int qbase = qt * 64 + wave * 16;
    const int qrow = qbase + l16;
    const int ntile = qt + 1;

    stage(0, 0);
    bf16x8 qf0 = *(const bf16x8*)&Qp[(size_t)(qbase + l16) * 64 + lhi * 8];
    bf16x8 qf1 = *(const bf16x8*)&Qp[(size_t)(qbase + l16) * 64 + 32 + lhi * 8];

    f32x4 o[4] = {};
    float mi = -1e30f, li = 0.f;

    asm volatile("s_waitcnt vmcnt(0)" ::: "memory");
    __syncthreads();

    int cur = 0;
#pragma unroll 1
    for (int kt = 0; kt < ntile; ++kt) {
      const int k0 = kt * 64;
      if (kt + 1 < ntile) stage(cur ^ 1, k0 + 64);

      const char* kb = (const char*)Ks[cur];
      f32x4 st[4];
      __builtin_amdgcn_s_setprio(1);
#pragma unroll
      for (int j = 0; j < 4; ++j) {
        const char* kr = kb + (16 * j + l16) * 128;
        bf16x8 kf0 = *(const bf16x8*)(kr + kc0);
        bf16x8 kf1 = *(const bf16x8*)(kr + (kc0 ^ 64));
        f32x4 z = {};
        z = __builtin_amdgcn_mfma_f32_16x16x32_bf16(kf0, qf0, z, 0, 0, 0);
        st[j] = __builtin_amdgcn_mfma_f32_16x16x32_bf16(kf1, qf1, z, 0, 0, 0);
      }
      __builtin_amdgcn_s_setprio(0);

      float p[16];
      float mv = -1e30f;
      if (k0 + 63 <= qbase) {
#pragma unroll
        for (int j = 0; j < 4; ++j)
#pragma unroll
          for (int r = 0; r < 4; ++r) {
            float v = st[j][r];
            p[j * 4 + r] = v;
            mv = fmaxf(mv, v);
          }
      } else {
#pragma unroll
        for (int j = 0; j < 4; ++j)
#pragma unroll
          for (int r = 0; r < 4; ++r) {
            int key = k0 + 16 * j + 4 * lhi + r;
            float v = (key <= qrow) ? st[j][r] : -1e30f;
            p[j * 4 + r] = v;
            mv = fmaxf(mv, v);
          }
      }
      mv = fmaxf(mv, __shfl_xor(mv, 16));
      mv = fmaxf(mv, __shfl_xor(mv, 32));
      if (!__all(mv <= mi + 8.0f)) {
        float mnew = fmaxf(mi, mv);
        float alpha = __builtin_amdgcn_exp2f(mi - mnew);
#pragma unroll
        for (int c = 0; c < 4; ++c)
#pragma unroll
          for (int r = 0; r < 4; ++r) o[c][r] *= alpha;
        li *= alpha;
        mi = mnew;
      }
      float sum = 0.f;
#pragma unroll
      for (int i = 0; i < 16; ++i) {
        p[i] = __builtin_amdgcn_exp2f(p[i] - mi);
        sum += p[i];
      }
      sum += __shfl_xor(sum, 16);
      sum += __shfl_xor(sum, 32);
      li += sum;

#pragma unroll
      for (int j = 0; j < 4; ++j) {
        uint2 w;
        w.x = cvt_pk_bf16(p[j * 4 + 0], p[j * 4 + 1]);
        w.y = cvt_pk_bf16(p[j * 4 + 2], p[j * 4 + 3]);
        *(uint2*)&Plds[wave][l16 * 64 + ((j * 16 + 4 * lhi) ^ swz)] = w;
      }
      asm volatile("s_waitcnt lgkmcnt(0)" ::: "memory");
      __builtin_amdgcn_sched_barrier(0);

      const char* vb = (const char*)Vs[cur];
      __builtin_amdgcn_s_setprio(1);
#pragma unroll
      for (int c2 = 0; c2 < 2; ++c2) {
        bf16x8 pf = *(const bf16x8*)&Plds[wave][l16 * 64 + ((c2 * 32 + lhi * 8) ^ swz)];
#pragma unroll
        for (int c = 0; c < 4; ++c) {
          bf16x8 vf = *(const bf16x8*)(vb + (c * 16 + l16) * 128 + (kc0 ^ (c2 * 64)));
          o[c] = __builtin_amdgcn_mfma_f32_16x16x32_bf16(vf, pf, o[c], 0, 0, 0);
        }
      }
      __builtin_amdgcn_s_setprio(0);

      asm volatile("s_waitcnt vmcnt(0)" ::: "memory");
      __syncthreads();
      cur ^= 1;
    }

    float invl = 1.0f / li;
    size_t rowb = (size_t)(b * 2048 + qbase + l16) * 1024 + h * 64;
#pragma unroll
    for (int c = 0; c < 4; ++c) {
      uint2 w;
      w.x = cvt_pk_bf16(o[c][0] * invl, o[c][1] * invl);
      w.y = cvt_pk_bf16(o[c][2] * invl, o[c][3] * invl);
      *(uint2*)&Ao[rowb + c * 16 + lhi * 4] = w;
    }
  }
}

extern "C" void kernel_launch(void* const* d_in, const int* in_sizes, int n_in,
                              void* d_out, int out_size, void* d_ws, size_t ws_size,
                              hipStream_t stream) {
  const float* X    = (const float*)d_in[0];
  const float* Wqkv = (const float*)d_in[1];
  const float* bqkv = (const float*)d_in[2];
  const float* Wout = (const float*)d_in[3];
  const float* bout = (const float*)d_in[4];
  float* out = (float*)d_out;

  unsigned short* ws     = (unsigned short*)d_ws;
  unsigned short* Xb     = ws;                   // 8192*1024
  unsigned short* Wqkv_t = Xb + 8388608;         // 3072*1024
  unsigned short* Wout_t = Wqkv_t + 3145728;     // 1024*1024
  unsigned short* Qb     = Wout_t + 1048576;     // [B,H,S,64]
  unsigned short* Kb     = Qb + 8388608;         // [B,H,S,64]
  unsigned short* Vtb    = Kb + 8388608;         // [B,H,64,S]
  unsigned short* Aob    = Vtb + 8388608;        // [B*S,1024]

  cvt_bf16_kernel<<<8192, 256, 0, stream>>>(X, Xb, 8388608);
  transpose_cvt_kernel<<<dim3(3072 / 32, 1024 / 32), 256, 0, stream>>>(Wqkv, Wqkv_t, 1024, 3072);
  transpose_cvt_kernel<<<dim3(1024 / 32, 1024 / 32), 256, 0, stream>>>(Wout, Wout_t, 1024, 1024);
  gemmW_kernel<1, 24><<<768, 256, 0, stream>>>(
      Xb, Wqkv_t, bqkv, nullptr, Qb, Kb, Vtb, 3072, 1024);
  attn_kernel<<<dim3(16, 64), 256, 0, stream>>>(Qb, Kb, Vtb, Aob);
  gemm3_kernel<0, 4><<<256, 512, 0, stream>>>(
      Aob, Wout_t, bout, out, nullptr, nullptr, nullptr, 1024, 1024);
}